// Round 11
// baseline (38.313 us; speedup 1.0000x reference)
//
#include <hip/hip_runtime.h>
#include <math.h>

// Problem: x[B=32][N=2048][K=8], W[N][C=32][J=16][K=8], R[N][C]
// out[b][c][j] = squash_j( sum_n softmax_n(R)[n,c] * sum_k W[n,c,j,k]*x[b,n,k] )
// This version: main accumulates with UNNORMALIZED w = exp(R[n][c]); reduce
// computes denominators sum_n exp(R[n][c]) itself and normalizes before squash.

#define NN 2048
#define CC 32

__device__ __forceinline__ void g2l16(const float* g, float* l) {
  __builtin_amdgcn_global_load_lds((const __attribute__((address_space(1))) void*)g,
                                   (__attribute__((address_space(3))) void*)l, 16, 0, 0);
}

// ---------- Kernel 1: c-octet, 2 n/wave, 16 waves/CU pipelined contraction ----------
// grid 512: chunk = bid&127 (16 n), cg = bid>>7 (8 c). XCD = bid%8 = chunk%8 -> the 4
// cg-blocks of a chunk share an XCD (x slice L2-resident). block 512 = 8 waves;
// LDS 80KB -> 2 blocks/CU = 16 waves/CU (4/SIMD) — R10's c-octet instr count
// (1024 ds_read_b128/CU) at R8's occupancy. Wave ws owns n = n0+ws*2, +1.
//   W: per n 256 granules (4 g2l16) into 2-buf ring; LDS slot S holds source granule
//      g = S ^ ((S>>3)&3); read slot = (ci*32+j*2+kh) ^ (j>>2)  [R10-verified]
//   x: per n 64 granules (1 g2l16; per-lane src does k<->b transpose);
//      slot S = G ^ ((G>>4)<<1), G = b*2+kq  [R7/R10-verified]
// Sync: explicit counted vmcnt before EVERY compute + sched_barrier(0) (R7/R10
// discipline; R9's barrier-implied drain raced). No ring wrap -> no WAR guard.
// NO occupancy attributes (R4/R6: they clamp VGPR to 64 -> ~60MB spill).
__global__ void __launch_bounds__(512) caps_main(const float* __restrict__ x,
                                                 const float* __restrict__ W,
                                                 const float* __restrict__ R,
                                                 float* __restrict__ P) {
  const int bid = blockIdx.x;
  const int cg = bid >> 7;       // c-octet 0..3
  const int chunk = bid & 127;   // 16-n chunk
  const int n0 = chunk * 16;
  const int tid = threadIdx.x;
  const int ws = tid >> 6;
  const int lane = tid & 63;
  const int j = lane & 15;
  const int bo = lane >> 4;

  extern __shared__ float smem[];   // 8 waves x 2560 floats = 80 KB
  float* wREG = smem + ws * 2560;
  float* wW = wREG;                 // 2 bufs x 1024 floats
  float* wX = wREG + 2048;          // 2 n x 256 floats
  const int nw = n0 + ws * 2;

  // ---- R loads first (oldest vmem-queue entries; values consumed pre-wait) ----
  float4 ra0 = *(const float4*)(R + (size_t)nw * CC + cg * 8);
  float4 ra1 = *(const float4*)(R + (size_t)nw * CC + cg * 8 + 4);
  float4 rb0 = *(const float4*)(R + (size_t)(nw + 1) * CC + cg * 8);
  float4 rb1 = *(const float4*)(R + (size_t)(nw + 1) * CC + cg * 8 + 4);

  auto stageW = [&](int nl, int buf) {
#pragma unroll
    for (int i = 0; i < 4; ++i) {
      int S = i * 64 + lane;
      int g = S ^ ((S >> 3) & 3);   // involution
      g2l16(W + (size_t)(nw + nl) * 4096 + cg * 1024 + g * 4,
            wW + buf * 1024 + i * 256);
    }
  };

  // ---- issue: W n0 -> buf0 (4), x both n (2), W n1 -> buf1 (4) ----
  stageW(0, 0);
  {
    int g2 = lane ^ ((lane >> 4) << 1);   // slot 'lane' holds granule g2
    int b = g2 >> 1, kq = g2 & 1;
    const float* xs = x + (size_t)b * (NN * 8) + kq * 4;
    g2l16(xs + (size_t)nw * 8, wX);
    g2l16(xs + (size_t)(nw + 1) * 8, wX + 256);
  }
  stageW(1, 1);

  // unnormalized routing weights (compiler auto-drains the R loads here)
  float rv[2][8];
  rv[0][0] = expf(ra0.x); rv[0][1] = expf(ra0.y); rv[0][2] = expf(ra0.z); rv[0][3] = expf(ra0.w);
  rv[0][4] = expf(ra1.x); rv[0][5] = expf(ra1.y); rv[0][6] = expf(ra1.z); rv[0][7] = expf(ra1.w);
  rv[1][0] = expf(rb0.x); rv[1][1] = expf(rb0.y); rv[1][2] = expf(rb0.z); rv[1][3] = expf(rb0.w);
  rv[1][4] = expf(rb1.x); rv[1][5] = expf(rb1.y); rv[1][6] = expf(rb1.z); rv[1][7] = expf(rb1.w);

  float acc[8][8];
#pragma unroll
  for (int a = 0; a < 8; ++a)
#pragma unroll
    for (int b = 0; b < 8; ++b) acc[a][b] = 0.f;

  auto compute = [&](int nl, int buf) {
    const float* Wn = wW + buf * 1024;
    const float* Xn = wX + nl * 256;
#pragma unroll
    for (int kh = 0; kh < 2; ++kh) {
      float4 xv[8];
#pragma unroll
      for (int bi = 0; bi < 8; ++bi) {
        int G = (bo * 8 + bi) * 2 + kh;
        int S = G ^ ((G >> 4) << 1);
        xv[bi] = *(const float4*)(Xn + S * 4);
      }
#pragma unroll
      for (int ci = 0; ci < 8; ++ci) {
        int slot = (ci * 32 + j * 2 + kh) ^ (j >> 2);
        float4 wf = *(const float4*)(Wn + slot * 4);
        float rvv = rv[nl][ci];
        float w0 = wf.x * rvv, w1 = wf.y * rvv, w2 = wf.z * rvv, w3 = wf.w * rvv;
#pragma unroll
        for (int bi = 0; bi < 8; ++bi) {
          float a = acc[ci][bi];
          a = fmaf(w0, xv[bi].x, a);
          a = fmaf(w1, xv[bi].y, a);
          a = fmaf(w2, xv[bi].z, a);
          a = fmaf(w3, xv[bi].w, a);
          acc[ci][bi] = a;
        }
      }
    }
  };

  // ---- pipeline: 2 counted waits, 0 barriers ----
  asm volatile("s_waitcnt vmcnt(4)" ::: "memory");    // W0 + x landed (W1 in flight)
  __builtin_amdgcn_sched_barrier(0);
  compute(0, 0);
  asm volatile("s_waitcnt vmcnt(0)" ::: "memory");    // W1 landed
  __builtin_amdgcn_sched_barrier(0);
  compute(1, 1);

  // ---- epilogue: 2 phases; dump is wave-PRIVATE (rows fit own 2560-f region) ----
#pragma unroll
  for (int phase = 0; phase < 2; ++phase) {
    // dump rows (ci-phase*4)*8+bi in own region (in-wave DS order: safe, no pre-barrier)
#pragma unroll
    for (int cl = 0; cl < 4; ++cl)
#pragma unroll
      for (int bi = 0; bi < 8; ++bi)
        wREG[(cl * 8 + bi) * 64 + lane] = acc[phase * 4 + cl][bi];
    __syncthreads();
    // wave ws sums rows ws*4..+4 across the 8 waves; coalesced P write
    {
      float ssum[4] = {0.f, 0.f, 0.f, 0.f};
#pragma unroll
      for (int w = 0; w < 8; ++w)
#pragma unroll
        for (int i = 0; i < 4; ++i)
          ssum[i] += smem[(size_t)w * 2560 + (ws * 4 + i) * 64 + lane];
#pragma unroll
      for (int i = 0; i < 4; ++i)
        P[(size_t)bid * 4096 + (phase * 32 + ws * 4 + i) * 64 + lane] = ssum[i];
    }
    __syncthreads();  // phase reads done before next phase's dump overwrites
  }
}

// ---------- Kernel 2: denominators + cross-chunk reduce + squash ----------
// 128 blocks x 128 threads; block covers outputs g = bid*128..+128 (8 c values).
// P[bid = cg*128 + ch][cell = (ci*8+bi)*64 + bo*16 + j]
__global__ void caps_reduce(const float* __restrict__ P, const float* __restrict__ R,
                            float* __restrict__ out) {
  const int t = threadIdx.x;
  const int bid = blockIdx.x;
  const int g = bid * 128 + t;   // b*512 + c*16 + j
  const int j = g & 15;
  const int c = (g >> 4) & 31;
  const int b = g >> 9;
  const int bo = b >> 3, bi = b & 7;
  const int cg = c >> 3, ci = c & 7;

  // denominators for this block's 8 c's: c0 = (bid*8)&31 (multiple of 8)
  __shared__ float red[128];
  __shared__ float invd[8];
  {
    const int cl = t & 7, nt = t >> 3;  // 16 n-groups
    const int c0 = (bid * 8) & 31;
    float s = 0.f;
#pragma unroll 8
    for (int i = 0; i < 128; ++i)
      s += expf(R[(size_t)(nt + i * 16) * CC + c0 + cl]);
    red[t] = s;
  }
  __syncthreads();
#pragma unroll
  for (int h = 8; h >= 1; h >>= 1) {
    if ((t >> 3) < h) red[t] += red[t + h * 8];
    __syncthreads();
  }
  if (t < 8) invd[t] = 1.0f / red[t];
  __syncthreads();

  const int idx = (ci * 8 + bi) * 64 + (bo * 16 + j);
  const float* Pq = P + (size_t)cg * 128 * 4096 + idx;
  float s = 0.f;
#pragma unroll 16
  for (int ch = 0; ch < 128; ++ch)
    s += Pq[(size_t)ch * 4096];
  s *= invd[c & 7];

  float sq = s * s;
  sq += __shfl_xor(sq, 8, 16);
  sq += __shfl_xor(sq, 4, 16);
  sq += __shfl_xor(sq, 2, 16);
  sq += __shfl_xor(sq, 1, 16);
  float ss = sq + 1e-7f;
  float scale = sqrtf(ss) / (1.0f + ss);
  out[g] = scale * s;
}

extern "C" void kernel_launch(void* const* d_in, const int* in_sizes, int n_in,
                              void* d_out, int out_size, void* d_ws, size_t ws_size,
                              hipStream_t stream) {
  const float* x = (const float*)d_in[0];   // 32*2048*8
  const float* W = (const float*)d_in[1];   // 2048*32*16*8
  const float* R = (const float*)d_in[2];   // 2048*32
  float* out = (float*)d_out;               // 32*32*16
  float* P = (float*)d_ws;                  // 512*4096 floats (8 MB)

  hipFuncSetAttribute((const void*)caps_main,
                      hipFuncAttributeMaxDynamicSharedMemorySize, 81920);

  caps_main<<<512, 512, 81920, stream>>>(x, W, R, P);
  caps_reduce<<<128, 128, 0, stream>>>(P, R, out);
}

// Round 12
// 28.389 us; speedup vs baseline: 1.3496x; 1.3496x over previous
//
#include <hip/hip_runtime.h>
#include <math.h>

// Problem: x[B=32][N=2048][K=8], W[N][C=32][J=16][K=8], R[N][C]
// out[b][c][j] = squash_j( sum_n softmax_n(R)[n,c] * sum_k W[n,c,j,k]*x[b,n,k] )
// Main accumulates with UNNORMALIZED w = exp(R[n][c]) (no stats dependency);
// reduce computes denominators itself and normalizes before squash. 2 nodes.

#define NN 2048
#define CC 32

__device__ __forceinline__ void g2l16(const float* g, float* l) {
  __builtin_amdgcn_global_load_lds((const __attribute__((address_space(1))) void*)g,
                                   (__attribute__((address_space(3))) void*)l, 16, 0, 0);
}

// ---------- Kernel 1: c-quad wave-private pipelined contraction (R8 = 26.9us) ----------
// grid 512: chunk = bid&63 (32 n), cq = bid>>6 (4 c). XCD = bid%8 = chunk%8 -> the 8
// cq-blocks of a chunk share an XCD (x slice L2-resident). block 512 = 8 waves;
// 64KB LDS -> 2 blocks/CU (16 waves/CU). Wave-private staging: wave ws owns
// n = n0+ws*4..+4, 2-buf W ring, counted vmcnt before EVERY compute (R7/R8 proven;
// barrier-implied drains raced in R9), sched_barrier(0) after each wait (rule #18).
// R loads issued FIRST (oldest queue entries) so the compiler's expf-wait is
// vmcnt(8), leaving all staging loads in flight (R10 refinement).
// NO occupancy attributes: measured (R4/R6) they clamp VGPR to 64 -> ~60MB spill.
__global__ void __launch_bounds__(512) caps_main(const float* __restrict__ x,
                                                 const float* __restrict__ W,
                                                 const float* __restrict__ R,
                                                 float* __restrict__ P) {
  const int bid = blockIdx.x;
  const int cq = bid >> 6;
  const int chunk = bid & 63;
  const int n0 = chunk * 32;
  const int tid = threadIdx.x;
  const int ws = tid >> 6;
  const int lane = tid & 63;
  const int j = lane & 15;
  const int bo = lane >> 4;

  extern __shared__ float smem[];   // 16384 floats (64 KB)
  float* ldsW = smem;               // [8 waves][2 bufs][512]
  float* ldsX = smem + 8192;        // [8 waves][4 n][256]
  float* wW = ldsW + ws * 1024;
  float* wX = ldsX + ws * 1024;
  const int nw = n0 + ws * 4;       // this wave's first n

  // ---- R loads first: oldest vmem-queue entries (vm 0..3) ----
  float4 rq[4];
#pragma unroll
  for (int nl = 0; nl < 4; ++nl)
    rq[nl] = *(const float4*)(R + (size_t)(nw + nl) * CC + cq * 4);

  auto stageW = [&](int nl, int buf) {
#pragma unroll
    for (int i = 0; i < 2; ++i) {
      int S = i * 64 + lane;
      int g = S ^ (((S >> 2) ^ (S >> 4)) & 1) ^ (((S >> 3) & 1) << 1) ^ (((S >> 4) & 1) << 2);
      g2l16(W + (size_t)(nw + nl) * 4096 + cq * 512 + g * 4, wW + buf * 512 + i * 256);
    }
  };

  // ---- issue: W n0 (vm 4-5), x all 4 n (vm 6-9), W n1 (vm 10-11) ----
  stageW(0, 0);
  {
    int g2 = lane ^ ((lane >> 4) << 1);   // slot 'lane' holds granule g2
    int b = g2 >> 1, kq = g2 & 1;
    const float* xs = x + (size_t)b * (NN * 8) + kq * 4;
#pragma unroll
    for (int nl = 0; nl < 4; ++nl)
      g2l16(xs + (size_t)(nw + nl) * 8, wX + nl * 256);
  }
  stageW(1, 1);

  // unnormalized routing weights (compiler waits vmcnt(8): only R retired)
  float rv[4][4];
#pragma unroll
  for (int nl = 0; nl < 4; ++nl) {
    rv[nl][0] = expf(rq[nl].x);
    rv[nl][1] = expf(rq[nl].y);
    rv[nl][2] = expf(rq[nl].z);
    rv[nl][3] = expf(rq[nl].w);
  }

  float acc[4][8];
#pragma unroll
  for (int a = 0; a < 4; ++a)
#pragma unroll
    for (int b = 0; b < 8; ++b) acc[a][b] = 0.f;

  const int jsw = j >> 1;

  auto compute = [&](int nl, int buf) {
    const float* Wn = wW + buf * 512;
    const float* Xn = wX + nl * 256;
#pragma unroll
    for (int kh = 0; kh < 2; ++kh) {
      float4 xv[8];
#pragma unroll
      for (int bi = 0; bi < 8; ++bi) {
        int G = (bo * 8 + bi) * 2 + kh;
        int S = G ^ ((G >> 4) << 1);
        xv[bi] = *(const float4*)(Xn + S * 4);
      }
#pragma unroll
      for (int ci = 0; ci < 4; ++ci) {
        int slot = (ci * 32 + j * 2 + kh) ^ jsw;
        float4 wf = *(const float4*)(Wn + slot * 4);
        float rvv = rv[nl][ci];
        float w0 = wf.x * rvv, w1 = wf.y * rvv, w2 = wf.z * rvv, w3 = wf.w * rvv;
#pragma unroll
        for (int bi = 0; bi < 8; ++bi) {
          float a = acc[ci][bi];
          a = fmaf(w0, xv[bi].x, a);
          a = fmaf(w1, xv[bi].y, a);
          a = fmaf(w2, xv[bi].z, a);
          a = fmaf(w3, xv[bi].w, a);
          acc[ci][bi] = a;
        }
      }
    }
  };

  // ---- pipeline (R8-verbatim): counted waits, 0 barriers ----
  asm volatile("s_waitcnt vmcnt(2)" ::: "memory");   // W0 + x landed (W1 in flight)
  __builtin_amdgcn_sched_barrier(0);
  compute(0, 0);
  __builtin_amdgcn_sched_barrier(0);                 // keep stage(2) after compute(0) reads
  stageW(2, 0);
  asm volatile("s_waitcnt vmcnt(2)" ::: "memory");   // W1 landed
  __builtin_amdgcn_sched_barrier(0);
  compute(1, 1);
  __builtin_amdgcn_sched_barrier(0);
  stageW(3, 1);
  asm volatile("s_waitcnt vmcnt(2)" ::: "memory");   // W2 landed
  __builtin_amdgcn_sched_barrier(0);
  compute(2, 0);
  asm volatile("s_waitcnt vmcnt(0)" ::: "memory");   // W3 landed
  __builtin_amdgcn_sched_barrier(0);
  compute(3, 1);

  // ---- epilogue (R8-verbatim): dump wave-own regions, 1 barrier, block-sum ----
#pragma unroll
  for (int ci = 0; ci < 4; ++ci)
#pragma unroll
    for (int bi = 0; bi < 8; ++bi) {
      int cell = (ci * 8 + bi) * 64 + lane;  // ci<2 <=> cell<1024
      float* dst = (ci < 2) ? (ldsW + ws * 1024 + cell)
                            : (ldsX + ws * 1024 + (cell - 1024));
      *dst = acc[ci][bi];
    }
  __syncthreads();
  {
    const int t4 = tid * 4;
    const bool lo = (t4 < 1024);
    float4 ssum = make_float4(0.f, 0.f, 0.f, 0.f);
#pragma unroll
    for (int w = 0; w < 8; ++w) {
      const float* src = lo ? (ldsW + w * 1024 + t4) : (ldsX + w * 1024 + (t4 - 1024));
      float4 v = *(const float4*)src;
      ssum.x += v.x; ssum.y += v.y; ssum.z += v.z; ssum.w += v.w;
    }
    *(float4*)(P + (size_t)bid * 2048 + t4) = ssum;
  }
}

// ---------- Kernel 2: denominators + cross-chunk reduce + squash ----------
// 64 blocks x 256 threads. Block covers g = bid*256..+256 -> 16 consecutive c
// (c0 = (bid*16)&31). Denominators computed in-kernel (unnormalized main).
// P[bid = cq*64 + ch][cell = (ci*8+bi)*64 + bo*16 + j], cq = c>>2, ci = c&3.
__global__ void caps_reduce(const float* __restrict__ P, const float* __restrict__ R,
                            float* __restrict__ out) {
  const int t = threadIdx.x;
  const int bid = blockIdx.x;

  __shared__ float red[256];   // [nf 16][cl 16]
  __shared__ float invd[16];
  {
    const int cl = t & 15, nf = t >> 4;
    const int c0 = (bid * 16) & 31;
    float s = 0.f;
#pragma unroll 16
    for (int i = 0; i < 128; ++i)
      s += expf(R[(size_t)(nf + i * 16) * CC + c0 + cl]);
    red[t] = s;
  }
  __syncthreads();
#pragma unroll
  for (int h = 8; h >= 1; h >>= 1) {
    if ((t >> 4) < h) red[t] += red[t + h * 16];
    __syncthreads();
  }
  if (t < 16) invd[t] = 1.0f / red[t];
  __syncthreads();

  const int g = bid * 256 + t;   // b*512 + c*16 + j
  const int j = g & 15;
  const int c = (g >> 4) & 31;
  const int b = g >> 9;
  const int bo = b >> 3, bi = b & 7;
  const int cq = c >> 2, ci = c & 3;
  const int idx = (ci * 8 + bi) * 64 + (bo * 16 + j);
  const float* Pq = P + (size_t)cq * 64 * 2048 + idx;

  float s = 0.f;
#pragma unroll 16
  for (int ch = 0; ch < 64; ++ch)
    s += Pq[(size_t)ch * 2048];
  s *= invd[t >> 4];

  float sq = s * s;
  sq += __shfl_xor(sq, 8, 16);
  sq += __shfl_xor(sq, 4, 16);
  sq += __shfl_xor(sq, 2, 16);
  sq += __shfl_xor(sq, 1, 16);
  float ss = sq + 1e-7f;
  float scale = sqrtf(ss) / (1.0f + ss);
  out[g] = scale * s;
}

extern "C" void kernel_launch(void* const* d_in, const int* in_sizes, int n_in,
                              void* d_out, int out_size, void* d_ws, size_t ws_size,
                              hipStream_t stream) {
  const float* x = (const float*)d_in[0];   // 32*2048*8
  const float* W = (const float*)d_in[1];   // 2048*32*16*8
  const float* R = (const float*)d_in[2];   // 2048*32
  float* out = (float*)d_out;               // 32*32*16
  float* P = (float*)d_ws;                  // 512*2048 floats (4 MB)

  hipFuncSetAttribute((const void*)caps_main,
                      hipFuncAttributeMaxDynamicSharedMemorySize, 65536);

  caps_main<<<512, 512, 65536, stream>>>(x, W, R, P);
  caps_reduce<<<64, 256, 0, stream>>>(P, R, out);
}

// Round 13
// 26.735 us; speedup vs baseline: 1.4331x; 1.0619x over previous
//
#include <hip/hip_runtime.h>
#include <math.h>

// Problem: x[B=32][N=2048][K=8], W[N][C=32][J=16][K=8], R[N][C]
// out[b][c][j] = squash_j( sum_n softmax_n(R)[n,c] * sum_k W[n,c,j,k]*x[b,n,k] )
// Main accumulates with UNNORMALIZED w = exp(R[n][c]); reduce computes the
// denominators (cheap per-c block) and normalizes before squash. 2 nodes.

#define NN 2048
#define CC 32

__device__ __forceinline__ void g2l16(const float* g, float* l) {
  __builtin_amdgcn_global_load_lds((const __attribute__((address_space(1))) void*)g,
                                   (__attribute__((address_space(3))) void*)l, 16, 0, 0);
}

// ---------- Kernel 1: c-quad wave-private contraction, 3-buf ring (2-ahead) ----------
// grid 512: chunk = bid&63 (32 n), cq = bid>>6 (4 c). XCD = bid%8 = chunk%8 -> the 8
// cq-blocks of a chunk share an XCD (x slice L2-resident). block 512 = 8 waves;
// LDS = 8 waves x 2560 f = 80KB -> 2 blocks/CU (16 waves/CU). Wave ws owns
// n = n0+ws*4..+4. Per-wave region: W ring 3x512 f + x 4x256 f.
//   W: per n 128 granules (2 g2l16); slot S holds source granule
//      g = S ^ bit0(S2^S4) ^ bit1(S3) ^ bit2(S4); read slot = (ci*32+j*2+kh)^(j>>1).
//   x: per n 64 granules (1 g2l16; per-lane src does k<->b transpose);
//      slot S = G ^ ((G>>4)<<1), G = b*2+kq.
// Issue order PINNED with sched_barrier(0) so counted-vmcnt arithmetic is exact
// (R9 lesson: unpinned reg-load/stage ordering corrupts the accounting).
// Counted vmcnt before EVERY compute (R7/R8/R12 proven); lgkmcnt(0) WAR guard
// before the ring-wrap stage. NO occupancy attributes (R4/R6: VGPR clamp -> spill).
__global__ void __launch_bounds__(512) caps_main(const float* __restrict__ x,
                                                 const float* __restrict__ W,
                                                 const float* __restrict__ R,
                                                 float* __restrict__ P) {
  const int bid = blockIdx.x;
  const int cq = bid >> 6;
  const int chunk = bid & 63;
  const int n0 = chunk * 32;
  const int tid = threadIdx.x;
  const int ws = tid >> 6;
  const int lane = tid & 63;
  const int j = lane & 15;
  const int bo = lane >> 4;

  extern __shared__ float smem[];   // 8 x 2560 floats = 80 KB
  float* wREG = smem + ws * 2560;
  float* wW = wREG;                 // ring: 3 bufs x 512
  float* wX = wREG + 1536;          // 4 n x 256
  const int nw = n0 + ws * 4;

  // ---- R loads first (pinned oldest) ----
  float4 rq[4];
#pragma unroll
  for (int nl = 0; nl < 4; ++nl)
    rq[nl] = *(const float4*)(R + (size_t)(nw + nl) * CC + cq * 4);
  __builtin_amdgcn_sched_barrier(0);

  auto stageW = [&](int nl, int buf) {
#pragma unroll
    for (int i = 0; i < 2; ++i) {
      int S = i * 64 + lane;
      int g = S ^ (((S >> 2) ^ (S >> 4)) & 1) ^ (((S >> 3) & 1) << 1) ^ (((S >> 4) & 1) << 2);
      g2l16(W + (size_t)(nw + nl) * 4096 + cq * 512 + g * 4, wW + buf * 512 + i * 256);
    }
  };

  // ---- prologue: W0, x, W1, W2 (pinned order; 10 g2l16 outstanding) ----
  stageW(0, 0);
  __builtin_amdgcn_sched_barrier(0);
  {
    int g2 = lane ^ ((lane >> 4) << 1);   // slot 'lane' holds granule g2
    int b = g2 >> 1, kq = g2 & 1;
    const float* xs = x + (size_t)b * (NN * 8) + kq * 4;
#pragma unroll
    for (int nl = 0; nl < 4; ++nl)
      g2l16(xs + (size_t)(nw + nl) * 8, wX + nl * 256);
  }
  __builtin_amdgcn_sched_barrier(0);
  stageW(1, 1);
  __builtin_amdgcn_sched_barrier(0);
  stageW(2, 2);
  __builtin_amdgcn_sched_barrier(0);

  // unnormalized routing weights (compiler auto-waits for the R loads only)
  float rv[4][4];
#pragma unroll
  for (int nl = 0; nl < 4; ++nl) {
    rv[nl][0] = expf(rq[nl].x);
    rv[nl][1] = expf(rq[nl].y);
    rv[nl][2] = expf(rq[nl].z);
    rv[nl][3] = expf(rq[nl].w);
  }

  float acc[4][8];
#pragma unroll
  for (int a = 0; a < 4; ++a)
#pragma unroll
    for (int b = 0; b < 8; ++b) acc[a][b] = 0.f;

  const int jsw = j >> 1;

  auto compute = [&](int nl, int buf) {
    const float* Wn = wW + buf * 512;
    const float* Xn = wX + nl * 256;
#pragma unroll
    for (int kh = 0; kh < 2; ++kh) {
      float4 xv[8];
#pragma unroll
      for (int bi = 0; bi < 8; ++bi) {
        int G = (bo * 8 + bi) * 2 + kh;
        int S = G ^ ((G >> 4) << 1);
        xv[bi] = *(const float4*)(Xn + S * 4);
      }
#pragma unroll
      for (int ci = 0; ci < 4; ++ci) {
        int slot = (ci * 32 + j * 2 + kh) ^ jsw;
        float4 wf = *(const float4*)(Wn + slot * 4);
        float rvv = rv[nl][ci];
        float w0 = wf.x * rvv, w1 = wf.y * rvv, w2 = wf.z * rvv, w3 = wf.w * rvv;
#pragma unroll
        for (int bi = 0; bi < 8; ++bi) {
          float a = acc[ci][bi];
          a = fmaf(w0, xv[bi].x, a);
          a = fmaf(w1, xv[bi].y, a);
          a = fmaf(w2, xv[bi].z, a);
          a = fmaf(w3, xv[bi].w, a);
          acc[ci][bi] = a;
        }
      }
    }
  };

  // ---- pipeline: 2-ahead ring; counted waits only; 0 barriers ----
  asm volatile("s_waitcnt vmcnt(4)" ::: "memory");   // W0 + x landed (W1,W2 in flight)
  __builtin_amdgcn_sched_barrier(0);
  compute(0, 0);
  asm volatile("s_waitcnt lgkmcnt(0)" ::: "memory"); // compute0 LDS reads retired
  __builtin_amdgcn_sched_barrier(0);
  stageW(3, 0);                                      // ring wrap onto buf0
  __builtin_amdgcn_sched_barrier(0);
  asm volatile("s_waitcnt vmcnt(4)" ::: "memory");   // W1 landed (W2,W3 in flight)
  __builtin_amdgcn_sched_barrier(0);
  compute(1, 1);
  asm volatile("s_waitcnt vmcnt(2)" ::: "memory");   // W2 landed (W3 in flight)
  __builtin_amdgcn_sched_barrier(0);
  compute(2, 2);
  asm volatile("s_waitcnt vmcnt(0)" ::: "memory");   // W3 landed
  __builtin_amdgcn_sched_barrier(0);
  compute(3, 0);

  // ---- epilogue: dump into own region (in-wave DS order safe), 1 barrier ----
#pragma unroll
  for (int ci = 0; ci < 4; ++ci)
#pragma unroll
    for (int bi = 0; bi < 8; ++bi)
      wREG[(ci * 8 + bi) * 64 + lane] = acc[ci][bi];
  __syncthreads();
  {
    const int t4 = tid * 4;
    float4 ssum = make_float4(0.f, 0.f, 0.f, 0.f);
#pragma unroll
    for (int w = 0; w < 8; ++w) {
      float4 v = *(const float4*)(smem + (size_t)w * 2560 + t4);
      ssum.x += v.x; ssum.y += v.y; ssum.z += v.z; ssum.w += v.w;
    }
    *(float4*)(P + (size_t)bid * 2048 + t4) = ssum;
  }
}

// ---------- Kernel 2: per-c denominator + float4 cross-chunk reduce + squash ----------
// 32 blocks (one per c) x 128 threads. t = b*4 + jq (b 0..31, jq 0..3).
// Denominator: 16 exp/thread + wave shfl reduce (1 barrier).
// P[bid = cq*64 + ch][cell = (ci*8+bi)*64 + bo*16 + j]; f4 over j-quad.
__global__ void caps_reduce(const float* __restrict__ P, const float* __restrict__ R,
                            float* __restrict__ out) {
  const int c = blockIdx.x;
  const int t = threadIdx.x;
  const int b = t >> 2, jq = t & 3;

  __shared__ float red[2];
  {
    float s = 0.f;
#pragma unroll
    for (int i = 0; i < 16; ++i)
      s += expf(R[(size_t)(t + i * 128) * CC + c]);
#pragma unroll
    for (int d = 32; d >= 1; d >>= 1) s += __shfl_xor(s, d, 64);
    if ((t & 63) == 0) red[t >> 6] = s;
  }
  __syncthreads();
  const float inv = 1.0f / (red[0] + red[1]);

  const int cq = c >> 2, ci = c & 3;
  const int bo = b >> 3, bi = b & 7;
  const int cell = (ci * 8 + bi) * 64 + bo * 16 + jq * 4;
  const float* Pq = P + (size_t)cq * 64 * 2048 + cell;

  float4 s4 = make_float4(0.f, 0.f, 0.f, 0.f);
#pragma unroll 16
  for (int ch = 0; ch < 64; ++ch) {
    float4 v = *(const float4*)(Pq + (size_t)ch * 2048);
    s4.x += v.x; s4.y += v.y; s4.z += v.z; s4.w += v.w;
  }
  s4.x *= inv; s4.y *= inv; s4.z *= inv; s4.w *= inv;

  // ||s||^2 over the 16 j of (b,c): 4 per thread + 4-lane group reduce
  float sq = s4.x * s4.x + s4.y * s4.y + s4.z * s4.z + s4.w * s4.w;
  sq += __shfl_xor(sq, 1, 4);
  sq += __shfl_xor(sq, 2, 4);
  float ss = sq + 1e-7f;
  float scale = sqrtf(ss) / (1.0f + ss);
  s4.x *= scale; s4.y *= scale; s4.z *= scale; s4.w *= scale;

  *(float4*)(out + (size_t)b * 512 + c * 16 + jq * 4) = s4;
}

extern "C" void kernel_launch(void* const* d_in, const int* in_sizes, int n_in,
                              void* d_out, int out_size, void* d_ws, size_t ws_size,
                              hipStream_t stream) {
  const float* x = (const float*)d_in[0];   // 32*2048*8
  const float* W = (const float*)d_in[1];   // 2048*32*16*8
  const float* R = (const float*)d_in[2];   // 2048*32
  float* out = (float*)d_out;               // 32*32*16
  float* P = (float*)d_ws;                  // 512*2048 floats (4 MB)

  hipFuncSetAttribute((const void*)caps_main,
                      hipFuncAttributeMaxDynamicSharedMemorySize, 81920);

  caps_main<<<512, 512, 81920, stream>>>(x, W, R, P);
  caps_reduce<<<32, 128, 0, stream>>>(P, R, out);
}